// Round 3
// baseline (97.499 us; speedup 1.0000x reference)
//
#include <hip/hip_runtime.h>
#include <math.h>

#define D 1024

typedef float floatx4 __attribute__((ext_vector_type(4)));

// Pre-kernel: cos(theta), sin(theta), exp(log_scale) tables into workspace.
__global__ void rsa_make_tables(const float* __restrict__ log_scale,
                                const float* __restrict__ theta,
                                float* __restrict__ tabc,
                                float* __restrict__ tabs,
                                float* __restrict__ tabsc) {
    int i = blockIdx.x * blockDim.x + threadIdx.x;
    if (i < D) {
        float t = theta[i];
        tabc[i]  = cosf(t);
        tabs[i]  = sinf(t);
        tabsc[i] = expf(log_scale[i]);
    }
}

// One wave (64 lanes) per row of length D=1024; lane owns 16 contiguous elems.
// Grid-stride persistent waves: tables register-cached once per wave, next
// row's x prefetched into registers while the current row computes.
__global__ __launch_bounds__(256) void rsa_rot_kernel(
    const float* __restrict__ x,
    const float* __restrict__ tabc,
    const float* __restrict__ tabs,
    const float* __restrict__ tabsc,
    float* __restrict__ out,
    int nrows)
{
    const int lane   = threadIdx.x & 63;
    const int wave   = threadIdx.x >> 6;
    const int gwave  = blockIdx.x * 4 + wave;
    const int nwaves = gridDim.x * 4;
    const int tbase  = lane * 16;

    // ---- tables: load once per wave, live in registers across all rows ----
    float cv[16], sv[16], scv[16];
    #pragma unroll
    for (int j = 0; j < 4; ++j) {
        float4 c = *reinterpret_cast<const float4*>(tabc + tbase + j * 4);
        cv[j*4+0] = c.x; cv[j*4+1] = c.y; cv[j*4+2] = c.z; cv[j*4+3] = c.w;
        float4 s = *reinterpret_cast<const float4*>(tabs + tbase + j * 4);
        sv[j*4+0] = s.x; sv[j*4+1] = s.y; sv[j*4+2] = s.z; sv[j*4+3] = s.w;
        float4 sc = *reinterpret_cast<const float4*>(tabsc + tbase + j * 4);
        scv[j*4+0] = sc.x; scv[j*4+1] = sc.y; scv[j*4+2] = sc.z; scv[j*4+3] = sc.w;
    }

    if (gwave >= nrows) return;

    // ---- prologue: load first row ----
    float xv[16];
    {
        const float* p = x + (size_t)gwave * D + (size_t)lane * 16;
        #pragma unroll
        for (int j = 0; j < 4; ++j) {
            float4 v = *reinterpret_cast<const float4*>(p + j * 4);
            xv[j*4+0] = v.x; xv[j*4+1] = v.y; xv[j*4+2] = v.z; xv[j*4+3] = v.w;
        }
    }

    for (int row = gwave; row < nrows; ) {
        const int nrow = row + nwaves;

        // ---- prefetch next row while this row computes ----
        float nx[16];
        if (nrow < nrows) {
            const float* p = x + (size_t)nrow * D + (size_t)lane * 16;
            #pragma unroll
            for (int j = 0; j < 4; ++j) {
                float4 v = *reinterpret_cast<const float4*>(p + j * 4);
                nx[j*4+0] = v.x; nx[j*4+1] = v.y; nx[j*4+2] = v.z; nx[j*4+3] = v.w;
            }
        }

        // ---- scale ----
        float xs[16];
        #pragma unroll
        for (int k = 0; k < 16; ++k) xs[k] = xv[k] * scv[k];

        const float xs_next0 = __shfl(xs[0], (lane + 1) & 63); // lane 63: garbage, fixed in pass 2
        const float xs0_g    = __shfl(xs[0], 0);               // carry_0 = xs[0]

        // ---- Pass 1: per-segment affine map carry_out = A*carry_in + B ----
        float A = 1.0f, Bv = 0.0f;
        #pragma unroll
        for (int k = 0; k < 16; ++k) {
            float xn = (k < 15) ? xs[k+1] : xs_next0;
            Bv = fmaf(sv[k], Bv, cv[k] * xn);
            A  = sv[k] * A;
        }

        // ---- inclusive affine scan across lanes (Hillis-Steele) ----
        #pragma unroll
        for (int d = 1; d < 64; d <<= 1) {
            float Ar = __shfl_up(A,  d);
            float Br = __shfl_up(Bv, d);
            if (lane >= d) {
                Bv = fmaf(A, Br, Bv);
                A  = A * Ar;
            }
        }

        // carry at entry of my segment
        float Ap = __shfl_up(A,  1);
        float Bp = __shfl_up(Bv, 1);
        float carry = (lane == 0) ? xs0_g : fmaf(Ap, xs0_g, Bp);

        // ---- Pass 2: replay, emit outputs (y overwrites xs in-place) ----
        float out0_b = 0.0f;
        float yfirst = 0.0f;
        #pragma unroll
        for (int k = 0; k < 16; ++k) {
            float xn = (k < 15) ? xs[k+1] : xs_next0;
            if (k == 15 && lane == 63) xn = out0_b;     // wrap: pairs with out_0
            float yk = fmaf(cv[k], carry, -sv[k] * xn);
            float nc = fmaf(sv[k], carry, cv[k] * xn);
            carry = nc;
            if (k == 0) out0_b = __shfl(yk, 0);         // broadcast out_0
            xs[k] = yk;                                  // xs[k] dead after step k-1
            if (k == 15) yfirst = nc;                    // lane63: new_first
        }
        float yf = __shfl(yfirst, 63);
        if (lane == 0) xs[0] = yf;                       // y[0] = new_first

        // ---- residual subtract + non-temporal store ----
        {
            float* po = out + (size_t)row * D + (size_t)lane * 16;
            #pragma unroll
            for (int j = 0; j < 4; ++j) {
                floatx4 v;
                v.x = xs[j*4+0] - xv[j*4+0];
                v.y = xs[j*4+1] - xv[j*4+1];
                v.z = xs[j*4+2] - xv[j*4+2];
                v.w = xs[j*4+3] - xv[j*4+3];
                __builtin_nontemporal_store(v, reinterpret_cast<floatx4*>(po + j * 4));
            }
        }

        row = nrow;
        if (nrow < nrows) {
            #pragma unroll
            for (int k = 0; k < 16; ++k) xv[k] = nx[k];
        }
    }
}

extern "C" void kernel_launch(void* const* d_in, const int* in_sizes, int n_in,
                              void* d_out, int out_size, void* d_ws, size_t ws_size,
                              hipStream_t stream) {
    const float* x         = (const float*)d_in[0];
    const float* log_scale = (const float*)d_in[1];
    const float* theta     = (const float*)d_in[2];
    float* outp = (float*)d_out;

    float* tabc  = (float*)d_ws;
    float* tabs  = tabc + D;
    float* tabsc = tabs + D;

    const int nrows = in_sizes[0] / D;   // B*S = 32768

    rsa_make_tables<<<(D + 255) / 256, 256, 0, stream>>>(log_scale, theta, tabc, tabs, tabsc);

    // 2048 blocks = 8192 waves; 4 rows per wave, tables loaded once per wave.
    int blocks = (nrows + 3) / 4;
    if (blocks > 2048) blocks = 2048;
    rsa_rot_kernel<<<blocks, 256, 0, stream>>>(x, tabc, tabs, tabsc, outp, nrows);
}

// Round 4
// 77.788 us; speedup vs baseline: 1.2534x; 1.2534x over previous
//
#include <hip/hip_runtime.h>
#include <math.h>

#define D 1024

typedef float floatx4 __attribute__((ext_vector_type(4)));

// Tables (workspace): [0..D) cos, [D..2D) sin, [2D..3D) cos*sc_next,
// [3D..4D) sin*sc_next, [4D] = exp(log_scale[0]).
// sc_next folds the per-column scale exp(log_scale) into the rotation
// coefficients so the scaled vector xs is never materialized in registers.
__global__ void rsa_make_tables(const float* __restrict__ log_scale,
                                const float* __restrict__ theta,
                                float* __restrict__ tab) {
    int i = blockIdx.x * blockDim.x + threadIdx.x;
    if (i < D) {
        float t = theta[i];
        float c = cosf(t), s = sinf(t);
        float scn = expf(log_scale[(i + 1) & (D - 1)]);
        tab[i]         = c;
        tab[D + i]     = s;
        tab[2 * D + i] = c * scn;
        tab[3 * D + i] = s * scn;
        if (i == 0) tab[4 * D] = expf(log_scale[0]);
    }
}

// One wave = 2 rows (ILP-2). Lane owns 16 contiguous columns. The sequential
// Givens cascade is an affine recurrence -> exact affine-map scan across lanes.
// __launch_bounds__(256,4): 128-VGPR budget so tables + both rows stay
// register-resident (R1 showed the compiler reloading tables mid-chain at 48 VGPR).
__global__ __launch_bounds__(256, 4) void rsa_rot_kernel(
    const float* __restrict__ x,
    const float* __restrict__ tab,
    float* __restrict__ out,
    int nrows)
{
    const int lane = threadIdx.x & 63;
    const int wave = threadIdx.x >> 6;
    const int pair = blockIdx.x * 4 + wave;
    const int rowA = pair * 2;
    const int rowB = rowA + 1;
    if (rowA >= nrows) return;
    const bool hasB = (rowB < nrows);
    const int tbase = lane * 16;

    // ---- issue x loads first (8 dwordx4 outstanding) ----
    float xa[16], xb[16];
    {
        const float* pa = x + (size_t)rowA * D + tbase;
        #pragma unroll
        for (int j = 0; j < 4; ++j) {
            float4 v = *reinterpret_cast<const float4*>(pa + j * 4);
            xa[j*4+0] = v.x; xa[j*4+1] = v.y; xa[j*4+2] = v.z; xa[j*4+3] = v.w;
        }
        const float* pb = x + (size_t)(hasB ? rowB : rowA) * D + tbase;
        #pragma unroll
        for (int j = 0; j < 4; ++j) {
            float4 v = *reinterpret_cast<const float4*>(pb + j * 4);
            xb[j*4+0] = v.x; xb[j*4+1] = v.y; xb[j*4+2] = v.z; xb[j*4+3] = v.w;
        }
    }

    // ---- tables (L1/L2-resident after first blocks) ----
    float cv[16], sv[16], csv[16], ssv[16];
    #pragma unroll
    for (int j = 0; j < 4; ++j) {
        float4 c = *reinterpret_cast<const float4*>(tab + tbase + j * 4);
        cv[j*4+0] = c.x; cv[j*4+1] = c.y; cv[j*4+2] = c.z; cv[j*4+3] = c.w;
        float4 s = *reinterpret_cast<const float4*>(tab + D + tbase + j * 4);
        sv[j*4+0] = s.x; sv[j*4+1] = s.y; sv[j*4+2] = s.z; sv[j*4+3] = s.w;
        float4 a = *reinterpret_cast<const float4*>(tab + 2 * D + tbase + j * 4);
        csv[j*4+0] = a.x; csv[j*4+1] = a.y; csv[j*4+2] = a.z; csv[j*4+3] = a.w;
        float4 b = *reinterpret_cast<const float4*>(tab + 3 * D + tbase + j * 4);
        ssv[j*4+0] = b.x; ssv[j*4+1] = b.y; ssv[j*4+2] = b.z; ssv[j*4+3] = b.w;
    }
    const float sc0 = tab[4 * D];   // uniform -> s_load

    // first x of right neighbor's segment (raw, unscaled)
    const float xnA0 = __shfl(xa[0], (lane + 1) & 63);
    const float xnB0 = __shfl(xb[0], (lane + 1) & 63);
    // carry_0 = sc_0 * x_0
    const float c0A = sc0 * __shfl(xa[0], 0);
    const float c0B = sc0 * __shfl(xb[0], 0);

    // ---- Pass 1: per-segment affine map (carry' = s*carry + cs*x_next) ----
    float Aa = 1.0f, Ba = 0.0f, Ab = 1.0f, Bb = 0.0f;
    #pragma unroll
    for (int k = 0; k < 16; ++k) {
        float xA = (k < 15) ? xa[k+1] : xnA0;
        float xB = (k < 15) ? xb[k+1] : xnB0;
        Ba = fmaf(sv[k], Ba, csv[k] * xA);
        Bb = fmaf(sv[k], Bb, csv[k] * xB);
        Aa = sv[k] * Aa;
        Ab = sv[k] * Ab;
    }

    // ---- inclusive affine scan across lanes (two independent chains) ----
    #pragma unroll
    for (int d = 1; d < 64; d <<= 1) {
        float ArA = __shfl_up(Aa, d), BrA = __shfl_up(Ba, d);
        float ArB = __shfl_up(Ab, d), BrB = __shfl_up(Bb, d);
        if (lane >= d) {
            Ba = fmaf(Aa, BrA, Ba);  Aa = Aa * ArA;
            Bb = fmaf(Ab, BrB, Bb);  Ab = Ab * ArB;
        }
    }

    // carry at entry of my segment
    float ApA = __shfl_up(Aa, 1), BpA = __shfl_up(Ba, 1);
    float ApB = __shfl_up(Ab, 1), BpB = __shfl_up(Bb, 1);
    float carA = (lane == 0) ? c0A : fmaf(ApA, c0A, BpA);
    float carB = (lane == 0) ? c0B : fmaf(ApB, c0B, BpB);

    // ---- Pass 2: replay; residual y-x overwrites x in place ----
    float out0A = 0.0f, out0B = 0.0f;
    float yfA = 0.0f,  yfB = 0.0f;
    #pragma unroll
    for (int k = 0; k < 16; ++k) {
        float yA, yB, ncA, ncB;
        if (k < 15) {
            float xA = xa[k+1], xB = xb[k+1];
            yA  = fmaf(cv[k], carA, -ssv[k] * xA);
            ncA = fmaf(sv[k], carA,  csv[k] * xA);
            yB  = fmaf(cv[k], carB, -ssv[k] * xB);
            ncB = fmaf(sv[k], carB,  csv[k] * xB);
        } else {
            // wrap step on lane 63 pairs with out_0 (unscaled output value)
            float xA = (lane == 63) ? out0A : xnA0;
            float xB = (lane == 63) ? out0B : xnB0;
            float my = (lane == 63) ? sv[15] : ssv[15];
            float mc = (lane == 63) ? cv[15] : csv[15];
            yA  = fmaf(cv[15], carA, -my * xA);
            ncA = fmaf(sv[15], carA,  mc * xA);
            yB  = fmaf(cv[15], carB, -my * xB);
            ncB = fmaf(sv[15], carB,  mc * xB);
        }
        carA = ncA; carB = ncB;
        if (k == 0) { out0A = __shfl(yA, 0); out0B = __shfl(yB, 0); }
        // residual in place: xa[k] no longer needed after this step
        xa[k] = yA - xa[k];
        xb[k] = yB - xb[k];
        if (k == 15) { yfA = ncA; yfB = ncB; }   // lane 63: new_first
    }
    yfA = __shfl(yfA, 63);
    yfB = __shfl(yfB, 63);
    if (lane == 0) {
        // y[0] must be new_first: xa[0] currently holds out0 - x0
        xa[0] = (yfA - out0A) + xa[0];
        xb[0] = (yfB - out0B) + xb[0];
    }

    // ---- store ----
    {
        float* pa = out + (size_t)rowA * D + tbase;
        #pragma unroll
        for (int j = 0; j < 4; ++j) {
            float4 v;
            v.x = xa[j*4+0]; v.y = xa[j*4+1]; v.z = xa[j*4+2]; v.w = xa[j*4+3];
            *reinterpret_cast<float4*>(pa + j * 4) = v;
        }
        if (hasB) {
            float* pb = out + (size_t)rowB * D + tbase;
            #pragma unroll
            for (int j = 0; j < 4; ++j) {
                float4 v;
                v.x = xb[j*4+0]; v.y = xb[j*4+1]; v.z = xb[j*4+2]; v.w = xb[j*4+3];
                *reinterpret_cast<float4*>(pb + j * 4) = v;
            }
        }
    }
}

extern "C" void kernel_launch(void* const* d_in, const int* in_sizes, int n_in,
                              void* d_out, int out_size, void* d_ws, size_t ws_size,
                              hipStream_t stream) {
    const float* x         = (const float*)d_in[0];
    const float* log_scale = (const float*)d_in[1];
    const float* theta     = (const float*)d_in[2];
    float* outp = (float*)d_out;
    float* tab  = (float*)d_ws;          // 4*D+1 floats

    const int nrows = in_sizes[0] / D;   // B*S = 32768

    rsa_make_tables<<<(D + 255) / 256, 256, 0, stream>>>(log_scale, theta, tab);

    const int npairs = (nrows + 1) / 2;          // 2 rows per wave
    const int blocks = (npairs + 3) / 4;         // 4 waves per block
    rsa_rot_kernel<<<blocks, 256, 0, stream>>>(x, tab, outp, nrows);
}

// Round 5
// 49.887 us; speedup vs baseline: 1.9544x; 1.5593x over previous
//
#include <hip/hip_runtime.h>
#include <math.h>

#define D 1024

// Tables: [0..D) cos, [D..2D) sin, [2D..3D) cos*sc_next, [3D..4D) sin*sc_next,
// [4D] = exp(log_scale[0]). Scale folded into rotation coefficients.
__global__ void rsa_make_tables(const float* __restrict__ log_scale,
                                const float* __restrict__ theta,
                                float* __restrict__ tab) {
    int i = blockIdx.x * blockDim.x + threadIdx.x;
    if (i < D) {
        float t = theta[i];
        float c = cosf(t), s = sinf(t);
        float scn = expf(log_scale[(i + 1) & (D - 1)]);
        tab[i]         = c;
        tab[D + i]     = s;
        tab[2 * D + i] = c * scn;
        tab[3 * D + i] = s * scn;
        if (i == 0) tab[4 * D] = expf(log_scale[0]);
    }
}

// One wave per row. Row = 4 chunks of 256 columns; lane owns 4 contiguous
// elements per chunk (c*256 + lane*4 + 0..3) -> every global access is a
// contiguous 1KB per wave. Hierarchical affine scan:
//   pass1: 4-step per-lane maps (4 chunks, ILP-4)
//   scan : 4 independent 64-lane Hillis-Steele scans
//   chain: 3 sequential chunk-map applications (lane-63 broadcasts)
//   pass2: 4 independent replays
__global__ __launch_bounds__(256, 4) void rsa_rot_kernel(
    const float* __restrict__ x,
    const float* __restrict__ tab,
    float* __restrict__ out,
    int nrows)
{
    const int lane = threadIdx.x & 63;
    const int wave = threadIdx.x >> 6;
    const int row  = blockIdx.x * 4 + wave;
    if (row >= nrows) return;

    const float* xrow = x + (size_t)row * D;
    const int    off  = lane * 4;

    // ---- issue ALL loads up front; sched_barrier pins them above the chain ----
    float4 xq[4], cq[4], sq[4], csq[4], ssq[4];
    #pragma unroll
    for (int c = 0; c < 4; ++c)
        xq[c] = *reinterpret_cast<const float4*>(xrow + c * 256 + off);
    #pragma unroll
    for (int c = 0; c < 4; ++c) {
        cq[c]  = *reinterpret_cast<const float4*>(tab +         c * 256 + off);
        sq[c]  = *reinterpret_cast<const float4*>(tab +     D + c * 256 + off);
        csq[c] = *reinterpret_cast<const float4*>(tab + 2 * D + c * 256 + off);
        ssq[c] = *reinterpret_cast<const float4*>(tab + 3 * D + c * 256 + off);
    }
    const float sc0 = tab[4 * D];          // uniform -> scalar load
    __builtin_amdgcn_sched_barrier(0);

    // ---- neighbor-first-x per chunk ----
    float xnb[4];
    #pragma unroll
    for (int c = 0; c < 4; ++c) {
        float nb = __shfl(xq[c].x, (lane + 1) & 63);
        if (c < 3) {
            float bc = __shfl(xq[c + 1].x, 0);   // lane63 crosses into next chunk
            nb = (lane == 63) ? bc : nb;
        }
        xnb[c] = nb;   // c==3, lane63: dead value (pass1 result unused, pass2 replaced)
    }
    const float carry0 = sc0 * __shfl(xq[0].x, 0);

    // ---- Pass 1: per-lane 4-step affine maps, 4 chunks (ILP-4) ----
    float A[4], Bv[4];
    #pragma unroll
    for (int c = 0; c < 4; ++c) {
        float a = 1.0f, b = 0.0f;
        b = fmaf(sq[c].x, b, csq[c].x * xq[c].y); a *= sq[c].x;
        b = fmaf(sq[c].y, b, csq[c].y * xq[c].z); a *= sq[c].y;
        b = fmaf(sq[c].z, b, csq[c].z * xq[c].w); a *= sq[c].z;
        b = fmaf(sq[c].w, b, csq[c].w * xnb[c]);  a *= sq[c].w;
        A[c] = a; Bv[c] = b;
    }

    // ---- 4 independent inclusive 64-lane affine scans ----
    #pragma unroll
    for (int d = 1; d < 64; d <<= 1) {
        float Ar[4], Br[4];
        #pragma unroll
        for (int c = 0; c < 4; ++c) { Ar[c] = __shfl_up(A[c], d); Br[c] = __shfl_up(Bv[c], d); }
        if (lane >= d) {
            #pragma unroll
            for (int c = 0; c < 4; ++c) { Bv[c] = fmaf(A[c], Br[c], Bv[c]); A[c] *= Ar[c]; }
        }
    }

    // ---- chunk chaining: entry carry e[c] = (F_{c-1} ∘ .. ∘ F_0)(carry0) ----
    float e[4];
    e[0] = carry0;
    {
        float Ga = 1.0f, Gb = 0.0f;
        #pragma unroll
        for (int c = 1; c < 4; ++c) {
            float Fa = __shfl(A[c - 1], 63), Fb = __shfl(Bv[c - 1], 63);
            Gb = fmaf(Fa, Gb, Fb);
            Ga = Fa * Ga;
            e[c] = fmaf(Ga, carry0, Gb);
        }
    }

    // ---- per-lane entry carries ----
    float carry[4];
    #pragma unroll
    for (int c = 0; c < 4; ++c) {
        float Ap = __shfl_up(A[c], 1), Bp = __shfl_up(Bv[c], 1);
        carry[c] = (lane == 0) ? e[c] : fmaf(Ap, e[c], Bp);
    }

    // ---- out_0 (pre-wrap value at position 0), uniform via broadcasts ----
    const float c_0  = __shfl(cq[0].x, 0);
    const float ss_0 = __shfl(ssq[0].x, 0);
    const float x_1  = __shfl(xq[0].y, 0);
    const float out0 = fmaf(c_0, carry0, -(ss_0 * x_1));

    // ---- Pass 2: replay 4 chunks independently; residual overwrites xq ----
    float nf = 0.0f;
    #pragma unroll
    for (int c = 0; c < 4; ++c) {
        float cr = carry[c];
        float y0 = fmaf(cq[c].x, cr, -(ssq[c].x * xq[c].y));
        cr       = fmaf(sq[c].x, cr,   csq[c].x * xq[c].y);
        float y1 = fmaf(cq[c].y, cr, -(ssq[c].y * xq[c].z));
        cr       = fmaf(sq[c].y, cr,   csq[c].y * xq[c].z);
        float y2 = fmaf(cq[c].z, cr, -(ssq[c].z * xq[c].w));
        cr       = fmaf(sq[c].z, cr,   csq[c].z * xq[c].w);
        float xl  = xnb[c];
        float mss = ssq[c].w, mcs = csq[c].w;
        if (c == 3) {                      // step 1023 on lane 63: pairs with out_0, raw coefs
            xl  = (lane == 63) ? out0     : xl;
            mss = (lane == 63) ? sq[c].w  : mss;
            mcs = (lane == 63) ? cq[c].w  : mcs;
        }
        float y3 = fmaf(cq[c].w, cr, -(mss * xl));
        cr       = fmaf(sq[c].w, cr,   mcs * xl);
        if (c == 3) nf = cr;               // lane63: new_first
        xq[c].x = y0 - xq[c].x;
        xq[c].y = y1 - xq[c].y;
        xq[c].z = y2 - xq[c].z;
        xq[c].w = y3 - xq[c].w;
    }
    nf = __shfl(nf, 63);
    if (lane == 0) xq[0].x = (nf - out0) + xq[0].x;   // y[0] = new_first

    // ---- contiguous stores ----
    float* orow = out + (size_t)row * D;
    #pragma unroll
    for (int c = 0; c < 4; ++c)
        *reinterpret_cast<float4*>(orow + c * 256 + off) = xq[c];
}

extern "C" void kernel_launch(void* const* d_in, const int* in_sizes, int n_in,
                              void* d_out, int out_size, void* d_ws, size_t ws_size,
                              hipStream_t stream) {
    const float* x         = (const float*)d_in[0];
    const float* log_scale = (const float*)d_in[1];
    const float* theta     = (const float*)d_in[2];
    float* outp = (float*)d_out;
    float* tab  = (float*)d_ws;          // 4*D+1 floats

    const int nrows = in_sizes[0] / D;   // B*S = 32768

    rsa_make_tables<<<(D + 255) / 256, 256, 0, stream>>>(log_scale, theta, tab);

    const int blocks = (nrows + 3) / 4;  // 1 row/wave, 4 waves/block
    rsa_rot_kernel<<<blocks, 256, 0, stream>>>(x, tab, outp, nrows);
}

// Round 6
// 44.734 us; speedup vs baseline: 2.1795x; 1.1152x over previous
//
#include <hip/hip_runtime.h>
#include <math.h>

#define D 1024

// Single fused kernel: one wave per row; lane owns 4 contiguous elements in
// each of 4 chunks of 256 (c*256 + lane*4) -> every global access is a
// contiguous 1KB/wave. cos/sin/exp computed in-register (TRANS pipe is idle;
// kills the serialized table pre-kernel and the table-load waits).
// Hierarchical affine scan: per-lane 4-step maps -> 4 independent 64-lane
// scans -> 3-step chunk chaining -> independent replays.
__global__ __launch_bounds__(256, 4) void rsa_rot_kernel(
    const float* __restrict__ x,
    const float* __restrict__ log_scale,
    const float* __restrict__ theta,
    float* __restrict__ out,
    int nrows)
{
    const int lane = threadIdx.x & 63;
    const int wave = threadIdx.x >> 6;
    const int row  = blockIdx.x * 4 + wave;
    if (row >= nrows) return;

    const float* xrow = x + (size_t)row * D;
    const int    off  = lane * 4;

    // ---- issue param loads first (retire first), x loads after ----
    float4 thq[4], lsq[4];
    #pragma unroll
    for (int c = 0; c < 4; ++c) {
        thq[c] = *reinterpret_cast<const float4*>(theta     + c * 256 + off);
        lsq[c] = *reinterpret_cast<const float4*>(log_scale + c * 256 + off);
    }
    float4 xq[4];
    #pragma unroll
    for (int c = 0; c < 4; ++c)
        xq[c] = *reinterpret_cast<const float4*>(xrow + c * 256 + off);
    __builtin_amdgcn_sched_barrier(0);

    // ---- in-register tables (waits only on thq/lsq; x still in flight) ----
    float4 cq[4], sq[4], eq[4];
    #pragma unroll
    for (int c = 0; c < 4; ++c) {
        cq[c].x = __cosf(thq[c].x); sq[c].x = __sinf(thq[c].x); eq[c].x = __expf(lsq[c].x);
        cq[c].y = __cosf(thq[c].y); sq[c].y = __sinf(thq[c].y); eq[c].y = __expf(lsq[c].y);
        cq[c].z = __cosf(thq[c].z); sq[c].z = __sinf(thq[c].z); eq[c].z = __expf(lsq[c].z);
        cq[c].w = __cosf(thq[c].w); sq[c].w = __sinf(thq[c].w); eq[c].w = __expf(lsq[c].w);
    }

    // ---- scaled vector xs = exp(ls) * x (raw x kept for the residual) ----
    float4 xsq[4];
    #pragma unroll
    for (int c = 0; c < 4; ++c) {
        xsq[c].x = eq[c].x * xq[c].x;
        xsq[c].y = eq[c].y * xq[c].y;
        xsq[c].z = eq[c].z * xq[c].z;
        xsq[c].w = eq[c].w * xq[c].w;
    }

    // ---- neighbor-first-xs per chunk ----
    float xnb[4];
    #pragma unroll
    for (int c = 0; c < 4; ++c) {
        float nb = __shfl(xsq[c].x, (lane + 1) & 63);
        if (c < 3) {
            float bc = __shfl(xsq[c + 1].x, 0);   // lane63 crosses into next chunk
            nb = (lane == 63) ? bc : nb;
        }
        xnb[c] = nb;   // c==3, lane63: dead (pass1 result unused, pass2 uses out0)
    }
    const float carry0 = __shfl(xsq[0].x, 0);     // carry_0 = xs[0]

    // ---- Pass 1: per-lane 4-step affine maps (carry' = s*carry + c*xs_next) ----
    float A[4], Bv[4];
    #pragma unroll
    for (int c = 0; c < 4; ++c) {
        float a = 1.0f, b = 0.0f;
        b = fmaf(sq[c].x, b, cq[c].x * xsq[c].y); a *= sq[c].x;
        b = fmaf(sq[c].y, b, cq[c].y * xsq[c].z); a *= sq[c].y;
        b = fmaf(sq[c].z, b, cq[c].z * xsq[c].w); a *= sq[c].z;
        b = fmaf(sq[c].w, b, cq[c].w * xnb[c]);   a *= sq[c].w;
        A[c] = a; Bv[c] = b;
    }

    // ---- 4 independent inclusive 64-lane affine scans ----
    #pragma unroll
    for (int d = 1; d < 64; d <<= 1) {
        float Ar[4], Br[4];
        #pragma unroll
        for (int c = 0; c < 4; ++c) { Ar[c] = __shfl_up(A[c], d); Br[c] = __shfl_up(Bv[c], d); }
        if (lane >= d) {
            #pragma unroll
            for (int c = 0; c < 4; ++c) { Bv[c] = fmaf(A[c], Br[c], Bv[c]); A[c] *= Ar[c]; }
        }
    }

    // ---- chunk chaining: entry carry e[c] = (F_{c-1} ∘ .. ∘ F_0)(carry0) ----
    float e[4];
    e[0] = carry0;
    {
        float Ga = 1.0f, Gb = 0.0f;
        #pragma unroll
        for (int c = 1; c < 4; ++c) {
            float Fa = __shfl(A[c - 1], 63), Fb = __shfl(Bv[c - 1], 63);
            Gb = fmaf(Fa, Gb, Fb);
            Ga = Fa * Ga;
            e[c] = fmaf(Ga, carry0, Gb);
        }
    }

    // ---- per-lane entry carries ----
    float carry[4];
    #pragma unroll
    for (int c = 0; c < 4; ++c) {
        float Ap = __shfl_up(A[c], 1), Bp = __shfl_up(Bv[c], 1);
        carry[c] = (lane == 0) ? e[c] : fmaf(Ap, e[c], Bp);
    }

    // ---- out_0 (pre-wrap value at position 0) ----
    const float c_0  = __shfl(cq[0].x, 0);
    const float s_0  = __shfl(sq[0].x, 0);
    const float xs_1 = __shfl(xsq[0].y, 0);
    const float out0 = fmaf(c_0, carry0, -(s_0 * xs_1));

    // ---- Pass 2: replay 4 chunks independently; residual overwrites xq ----
    float nf = 0.0f;
    #pragma unroll
    for (int c = 0; c < 4; ++c) {
        float cr = carry[c];
        float y0 = fmaf(cq[c].x, cr, -(sq[c].x * xsq[c].y));
        cr       = fmaf(sq[c].x, cr,   cq[c].x * xsq[c].y);
        float y1 = fmaf(cq[c].y, cr, -(sq[c].y * xsq[c].z));
        cr       = fmaf(sq[c].y, cr,   cq[c].y * xsq[c].z);
        float y2 = fmaf(cq[c].z, cr, -(sq[c].z * xsq[c].w));
        cr       = fmaf(sq[c].z, cr,   cq[c].z * xsq[c].w);
        float xl = xnb[c];
        if (c == 3) xl = (lane == 63) ? out0 : xl;   // wrap: pairs with out_0
        float y3 = fmaf(cq[c].w, cr, -(sq[c].w * xl));
        cr       = fmaf(sq[c].w, cr,   cq[c].w * xl);
        if (c == 3) nf = cr;                          // lane63: new_first
        xq[c].x = y0 - xq[c].x;
        xq[c].y = y1 - xq[c].y;
        xq[c].z = y2 - xq[c].z;
        xq[c].w = y3 - xq[c].w;
    }
    nf = __shfl(nf, 63);
    if (lane == 0) xq[0].x = (nf - out0) + xq[0].x;   // y[0] = new_first - x[0]

    // ---- contiguous stores ----
    float* orow = out + (size_t)row * D;
    #pragma unroll
    for (int c = 0; c < 4; ++c)
        *reinterpret_cast<float4*>(orow + c * 256 + off) = xq[c];
}

extern "C" void kernel_launch(void* const* d_in, const int* in_sizes, int n_in,
                              void* d_out, int out_size, void* d_ws, size_t ws_size,
                              hipStream_t stream) {
    const float* x         = (const float*)d_in[0];
    const float* log_scale = (const float*)d_in[1];
    const float* theta     = (const float*)d_in[2];
    float* outp = (float*)d_out;

    const int nrows = in_sizes[0] / D;   // B*S = 32768

    const int blocks = (nrows + 3) / 4;  // 1 row/wave, 4 waves/block
    rsa_rot_kernel<<<blocks, 256, 0, stream>>>(x, log_scale, theta, outp, nrows);
}